// Round 1
// baseline (23357.143 us; speedup 1.0000x reference)
//
#include <hip/hip_runtime.h>
#include <hip/hip_bf16.h>
#include <math.h>

#define E_DIM 1024
#define H_DIM 2048
#define H3 6144
#define VOCAB 256
#define NWG 256
#define TPW 192   // 24 rows * 8 lanes/row = 3 waves

// ---------------- Phase A: table[v][j] = b_ih[j] + sum_e emb[v,e]*w_ih[j,e]
// BM=64 (v), BN=64 (j), BK=32, 256 threads, 4x4 microtile per thread.
__global__ __launch_bounds__(256) void ih_table_kernel(
    const float* __restrict__ emb, const float* __restrict__ w_ih,
    const float* __restrict__ b_ih, float* __restrict__ table)
{
    __shared__ float As[32][65];   // +1 pad: conflict-free transposed store
    __shared__ float Bs[32][65];
    const int v0 = blockIdx.y * 64;
    const int j0 = blockIdx.x * 64;
    const int t  = threadIdx.x;
    const int tx = t % 16, ty = t / 16;
    const int lr0 = t / 8;          // 0..31, row within tile (two passes)
    const int lc  = (t % 8) * 4;    // col offset (float4)
    float acc[4][4] = {};

    for (int k0 = 0; k0 < E_DIM; k0 += 32) {
        __syncthreads();
#pragma unroll
        for (int p = 0; p < 2; ++p) {
            int r = lr0 + p * 32;
            float4 a = *(const float4*)(emb  + (size_t)(v0 + r) * E_DIM + k0 + lc);
            As[lc+0][r] = a.x; As[lc+1][r] = a.y; As[lc+2][r] = a.z; As[lc+3][r] = a.w;
            float4 b = *(const float4*)(w_ih + (size_t)(j0 + r) * E_DIM + k0 + lc);
            Bs[lc+0][r] = b.x; Bs[lc+1][r] = b.y; Bs[lc+2][r] = b.z; Bs[lc+3][r] = b.w;
        }
        __syncthreads();
#pragma unroll 8
        for (int kk = 0; kk < 32; ++kk) {
            float a4[4], b4[4];
#pragma unroll
            for (int i = 0; i < 4; ++i) a4[i] = As[kk][ty * 4 + i];
#pragma unroll
            for (int i = 0; i < 4; ++i) b4[i] = Bs[kk][tx * 4 + i];
#pragma unroll
            for (int i = 0; i < 4; ++i)
#pragma unroll
                for (int j = 0; j < 4; ++j) acc[i][j] += a4[i] * b4[j];
        }
    }
    const int j = j0 + tx * 4;
    float4 bias = *(const float4*)(b_ih + j);
#pragma unroll
    for (int i = 0; i < 4; ++i) {
        int v = v0 + ty * 4 + i;
        float4 o;
        o.x = acc[i][0] + bias.x; o.y = acc[i][1] + bias.y;
        o.z = acc[i][2] + bias.z; o.w = acc[i][3] + bias.w;
        *(float4*)(table + (size_t)v * H3 + j) = o;
    }
}

// ---------------- Phase B: persistent GRU recurrence.
// WG w owns hidden units [w*8, w*8+8) -> 24 rows of W_hh (r,z,n gates).
// Thread layout: lr = tid/8 in [0,24) is local row, klane = tid&7 splits K.
__global__ __launch_bounds__(TPW) void gru_persistent(
    const int* __restrict__ x, const int* __restrict__ lenp,
    const float* __restrict__ w_hh, const float* __restrict__ b_hh,
    const float* __restrict__ table,
    float* hbuf0, float* hbuf1, unsigned* barcnt)
{
    __shared__ float hsh[H_DIM];
    __shared__ float dots[24];
    const int w     = blockIdx.x;
    const int tid   = threadIdx.x;
    const int base  = w * 8;
    const int lr    = tid >> 3;      // 0..23
    const int klane = tid & 7;       // 0..7
    const int gate  = lr >> 3;       // 0=r 1=z 2=n
    const int uu    = lr & 7;
    const int grow  = gate * H_DIM + base + uu;
    const float4* wrow = (const float4*)(w_hh + (size_t)grow * H_DIM);
    const int S = lenp[0] + 1;       // 1025
    float* bufs[2] = {hbuf0, hbuf1};

    for (int s = 0; s < S; ++s) {
        float* cur = bufs[s & 1];
        float* nxt = bufs[(s + 1) & 1];
        // stage h (agent-scope loads: cross-XCD L2s are not coherent)
        for (int i = tid; i < H_DIM; i += TPW)
            hsh[i] = __hip_atomic_load(cur + i, __ATOMIC_RELAXED,
                                       __HIP_MEMORY_SCOPE_AGENT);
        __syncthreads();

        const float4* h4 = (const float4*)hsh;
        float4 a = make_float4(0.f, 0.f, 0.f, 0.f);
#pragma unroll 8
        for (int i = 0; i < 64; ++i) {      // row-group reads 128B contiguous
            float4 wv = wrow[i * 8 + klane];
            float4 hv = h4[i * 8 + klane];
            a.x += wv.x * hv.x; a.y += wv.y * hv.y;
            a.z += wv.z * hv.z; a.w += wv.w * hv.w;
        }
        float p = (a.x + a.y) + (a.z + a.w);
        p += __shfl_xor(p, 1, 64);
        p += __shfl_xor(p, 2, 64);
        p += __shfl_xor(p, 4, 64);
        if (klane == 0) dots[lr] = p;
        __syncthreads();

        if (tid < 8) {
            const int u = base + tid;
            const float* trow = table + (size_t)x[s] * H3;
            float ihr = trow[u];
            float ihz = trow[H_DIM + u];
            float ihn = trow[2 * H_DIM + u];
            float hr = dots[tid]      + b_hh[u];
            float hz = dots[8 + tid]  + b_hh[H_DIM + u];
            float hn = dots[16 + tid] + b_hh[2 * H_DIM + u];
            float r_ = 1.f / (1.f + expf(-(ihr + hr)));
            float z_ = 1.f / (1.f + expf(-(ihz + hz)));
            float n_ = tanhf(ihn + r_ * hn);
            float hnew = (1.f - z_) * n_ + z_ * hsh[u];
            __hip_atomic_store(nxt + u, hnew, __ATOMIC_RELAXED,
                               __HIP_MEMORY_SCOPE_AGENT);
        }
        // grid barrier: cumulative counter, device scope
        __syncthreads();
        if (tid == 0) {
            __hip_atomic_fetch_add(barcnt, 1u, __ATOMIC_ACQ_REL,
                                   __HIP_MEMORY_SCOPE_AGENT);
            const unsigned target = (unsigned)(s + 1) * gridDim.x;
            while (__hip_atomic_load(barcnt, __ATOMIC_ACQUIRE,
                                     __HIP_MEMORY_SCOPE_AGENT) < target)
                __builtin_amdgcn_s_sleep(2);
        }
        __syncthreads();
    }
}

// ---------------- Epilogue: out = [dec_emb[2] (1024) | h_final (2048)]
__global__ void epilogue_kernel(const int* __restrict__ lenp,
                                const float* __restrict__ dec_emb,
                                const float* __restrict__ hbuf0,
                                const float* __restrict__ hbuf1,
                                float* __restrict__ out)
{
    int i = blockIdx.x * blockDim.x + threadIdx.x;
    int S = lenp[0] + 1;
    const float* hb = (S & 1) ? hbuf1 : hbuf0;
    if (i < E_DIM) out[i] = dec_emb[2 * E_DIM + i];
    else if (i < E_DIM + H_DIM) out[i] = hb[i - E_DIM];
}

extern "C" void kernel_launch(void* const* d_in, const int* in_sizes, int n_in,
                              void* d_out, int out_size, void* d_ws, size_t ws_size,
                              hipStream_t stream) {
    const int*   x       = (const int*)d_in[0];
    const int*   lenp    = (const int*)d_in[1];
    const float* emb     = (const float*)d_in[2];
    const float* w_ih    = (const float*)d_in[3];
    const float* w_hh    = (const float*)d_in[4];
    const float* b_ih    = (const float*)d_in[5];
    const float* b_hh    = (const float*)d_in[6];
    const float* dec_emb = (const float*)d_in[7];
    float* out = (float*)d_out;

    char* ws = (char*)d_ws;
    float* table   = (float*)ws;                           // 256*6144*4 = 6291456 B
    float* hbuf0   = (float*)(ws + (size_t)VOCAB * H3 * 4);
    float* hbuf1   = hbuf0 + H_DIM;
    unsigned* barcnt = (unsigned*)(hbuf1 + H_DIM);

    // zero h0 + barrier counter (ws is poisoned 0xAA before every call)
    hipMemsetAsync(hbuf0, 0, (size_t)(2 * H_DIM) * 4 + 64, stream);

    dim3 gA(H3 / 64, VOCAB / 64);  // (96, 4)
    ih_table_kernel<<<gA, 256, 0, stream>>>(emb, w_ih, b_ih, table);

    gru_persistent<<<dim3(NWG), dim3(TPW), 0, stream>>>(
        x, lenp, w_hh, b_hh, table, hbuf0, hbuf1, barcnt);

    epilogue_kernel<<<12, 256, 0, stream>>>(lenp, dec_emb, hbuf0, hbuf1, out);
}

// Round 2
// 12907.820 us; speedup vs baseline: 1.8095x; 1.8095x over previous
//
#include <hip/hip_runtime.h>
#include <hip/hip_bf16.h>
#include <math.h>

#define E_DIM 1024
#define H_DIM 2048
#define H3 6144
#define VOCAB 256
#define NCOMP 256          // compute workgroups (1..256); block 0 coordinates
#define TPW 384            // 24 rows * 16 lanes/row = 6 waves

typedef unsigned long long u64;

// ---------------- Phase A: table[v][j] = b_ih[j] + sum_e emb[v,e]*w_ih[j,e]
__global__ __launch_bounds__(256) void ih_table_kernel(
    const float* __restrict__ emb, const float* __restrict__ w_ih,
    const float* __restrict__ b_ih, float* __restrict__ table)
{
    __shared__ float As[32][65];
    __shared__ float Bs[32][65];
    const int v0 = blockIdx.y * 64;
    const int j0 = blockIdx.x * 64;
    const int t  = threadIdx.x;
    const int tx = t % 16, ty = t / 16;
    const int lr0 = t / 8;
    const int lc  = (t % 8) * 4;
    float acc[4][4] = {};

    for (int k0 = 0; k0 < E_DIM; k0 += 32) {
        __syncthreads();
#pragma unroll
        for (int p = 0; p < 2; ++p) {
            int r = lr0 + p * 32;
            float4 a = *(const float4*)(emb  + (size_t)(v0 + r) * E_DIM + k0 + lc);
            As[lc+0][r] = a.x; As[lc+1][r] = a.y; As[lc+2][r] = a.z; As[lc+3][r] = a.w;
            float4 b = *(const float4*)(w_ih + (size_t)(j0 + r) * E_DIM + k0 + lc);
            Bs[lc+0][r] = b.x; Bs[lc+1][r] = b.y; Bs[lc+2][r] = b.z; Bs[lc+3][r] = b.w;
        }
        __syncthreads();
#pragma unroll 8
        for (int kk = 0; kk < 32; ++kk) {
            float a4[4], b4[4];
#pragma unroll
            for (int i = 0; i < 4; ++i) a4[i] = As[kk][ty * 4 + i];
#pragma unroll
            for (int i = 0; i < 4; ++i) b4[i] = Bs[kk][tx * 4 + i];
#pragma unroll
            for (int i = 0; i < 4; ++i)
#pragma unroll
                for (int j = 0; j < 4; ++j) acc[i][j] += a4[i] * b4[j];
        }
    }
    const int j = j0 + tx * 4;
    float4 bias = *(const float4*)(b_ih + j);
#pragma unroll
    for (int i = 0; i < 4; ++i) {
        int v = v0 + ty * 4 + i;
        float4 o;
        o.x = acc[i][0] + bias.x; o.y = acc[i][1] + bias.y;
        o.z = acc[i][2] + bias.z; o.w = acc[i][3] + bias.w;
        *(float4*)(table + (size_t)v * H3 + j) = o;
    }
}

// ---------------- Phase B: persistent GRU with flag/epoch barrier.
// Block 0 = coordinator: thread t polls flags[t]; broadcasts epoch.
// Blocks 1..256: compute WG cw owns hidden units [cw*8, cw*8+8).
__global__ __launch_bounds__(TPW) void gru_persistent(
    const int* __restrict__ x, const int* __restrict__ lenp,
    const float* __restrict__ w_hh, const float* __restrict__ b_hh,
    const float* __restrict__ table,
    float* hbuf0, float* hbuf1, int* flags, int* epoch)
{
    const int w   = blockIdx.x;
    const int tid = threadIdx.x;
    const int S   = lenp[0] + 1;   // 1025

    if (w == 0) {
        // Coordinator: detect all-arrived for each step, publish epoch.
        for (int s = 0; s < S; ++s) {
            if (tid < NCOMP) {
                while (__hip_atomic_load(flags + tid * 32, __ATOMIC_RELAXED,
                                         __HIP_MEMORY_SCOPE_AGENT) < s + 1)
                    __builtin_amdgcn_s_sleep(1);
            }
            __syncthreads();
            if (tid == 0) {
                __threadfence();
                __hip_atomic_store(epoch, s + 1, __ATOMIC_RELAXED,
                                   __HIP_MEMORY_SCOPE_AGENT);
            }
        }
        return;
    }

    __shared__ float hsh[H_DIM];
    __shared__ float dots[24];
    const int cw    = w - 1;
    const int base  = cw * 8;
    const int lr    = tid >> 4;      // 0..23 local row
    const int klane = tid & 15;      // 16 lanes split K
    const int gate  = lr >> 3;       // 0=r 1=z 2=n
    const int uu    = lr & 7;
    const float4* wrow =
        (const float4*)(w_hh + (size_t)(gate * H_DIM + base + uu) * H_DIM);
    float* bufs[2] = {hbuf0, hbuf1};

    for (int s = 0; s < S; ++s) {
        // wait until h_s is published (h_0 ready via stream-ordered memset)
        if (s > 0 && tid == 0) {
            while (__hip_atomic_load(epoch, __ATOMIC_RELAXED,
                                     __HIP_MEMORY_SCOPE_AGENT) < s)
                __builtin_amdgcn_s_sleep(1);
        }
        __syncthreads();
        float* cur = bufs[s & 1];
        float* nxt = bufs[(s + 1) & 1];

        // stage h (agent-scope 8B loads: bypass stale per-XCD L2 lines)
        const u64* src = (const u64*)cur;
        u64* dsh = (u64*)hsh;
        for (int i = tid; i < H_DIM / 2; i += TPW)
            dsh[i] = __hip_atomic_load(src + i, __ATOMIC_RELAXED,
                                       __HIP_MEMORY_SCOPE_AGENT);
        __syncthreads();

        const float4* h4 = (const float4*)hsh;
        float4 a = make_float4(0.f, 0.f, 0.f, 0.f);
#pragma unroll 8
        for (int i = 0; i < 32; ++i) {   // 16 lanes * 16B = 256B contiguous/row
            float4 wv = wrow[i * 16 + klane];
            float4 hv = h4[i * 16 + klane];
            a.x += wv.x * hv.x; a.y += wv.y * hv.y;
            a.z += wv.z * hv.z; a.w += wv.w * hv.w;
        }
        float p = (a.x + a.y) + (a.z + a.w);
        p += __shfl_xor(p, 1);
        p += __shfl_xor(p, 2);
        p += __shfl_xor(p, 4);
        p += __shfl_xor(p, 8);
        if (klane == 0) dots[lr] = p;
        __syncthreads();

        if (tid < 8) {
            const int u = base + tid;
            const float* trow = table + (size_t)x[s] * H3;
            float ihr = trow[u];
            float ihz = trow[H_DIM + u];
            float ihn = trow[2 * H_DIM + u];
            float hr = dots[tid]      + b_hh[u];
            float hz = dots[8 + tid]  + b_hh[H_DIM + u];
            float hn = dots[16 + tid] + b_hh[2 * H_DIM + u];
            float r_ = 1.f / (1.f + expf(-(ihr + hr)));
            float z_ = 1.f / (1.f + expf(-(ihz + hz)));
            float n_ = tanhf(ihn + r_ * hn);
            float hnew = (1.f - z_) * n_ + z_ * hsh[u];
            __hip_atomic_store(nxt + u, hnew, __ATOMIC_RELAXED,
                               __HIP_MEMORY_SCOPE_AGENT);
        }
        __syncthreads();  // barrier drains vmcnt -> h stores agent-visible
        if (tid == 0) {
            __threadfence();
            __hip_atomic_store(flags + cw * 32, s + 1, __ATOMIC_RELAXED,
                               __HIP_MEMORY_SCOPE_AGENT);
        }
    }
}

// ---------------- Epilogue: out = [dec_emb[2] (1024) | h_final (2048)]
__global__ void epilogue_kernel(const int* __restrict__ lenp,
                                const float* __restrict__ dec_emb,
                                const float* __restrict__ hbuf0,
                                const float* __restrict__ hbuf1,
                                float* __restrict__ out)
{
    int i = blockIdx.x * blockDim.x + threadIdx.x;
    int S = lenp[0] + 1;
    const float* hb = (S & 1) ? hbuf1 : hbuf0;
    if (i < E_DIM) out[i] = dec_emb[2 * E_DIM + i];
    else if (i < E_DIM + H_DIM) out[i] = hb[i - E_DIM];
}

extern "C" void kernel_launch(void* const* d_in, const int* in_sizes, int n_in,
                              void* d_out, int out_size, void* d_ws, size_t ws_size,
                              hipStream_t stream) {
    const int*   x       = (const int*)d_in[0];
    const int*   lenp    = (const int*)d_in[1];
    const float* emb     = (const float*)d_in[2];
    const float* w_ih    = (const float*)d_in[3];
    const float* w_hh    = (const float*)d_in[4];
    const float* b_ih    = (const float*)d_in[5];
    const float* b_hh    = (const float*)d_in[6];
    const float* dec_emb = (const float*)d_in[7];
    float* out = (float*)d_out;

    char* ws = (char*)d_ws;
    float* table = (float*)ws;                              // 6,291,456 B
    float* hbuf0 = (float*)(ws + (size_t)VOCAB * H3 * 4);
    float* hbuf1 = hbuf0 + H_DIM;
    int*   flags = (int*)(hbuf1 + H_DIM);                   // 256 * 128 B
    int*   epoch = flags + NCOMP * 32;

    // zero h0/h1 + flags + epoch (ws is poisoned 0xAA before every call)
    hipMemsetAsync(hbuf0, 0,
                   (size_t)(2 * H_DIM) * 4 + (size_t)NCOMP * 128 + 128, stream);

    dim3 gA(H3 / 64, VOCAB / 64);  // (96, 4)
    ih_table_kernel<<<gA, 256, 0, stream>>>(emb, w_ih, b_ih, table);

    gru_persistent<<<dim3(NCOMP + 1), dim3(TPW), 0, stream>>>(
        x, lenp, w_hh, b_hh, table, hbuf0, hbuf1, flags, epoch);

    epilogue_kernel<<<12, 256, 0, stream>>>(lenp, dec_emb, hbuf0, hbuf1, out);
}

// Round 3
// 6809.263 us; speedup vs baseline: 3.4302x; 1.8956x over previous
//
#include <hip/hip_runtime.h>
#include <hip/hip_bf16.h>
#include <math.h>

#define E_DIM 1024
#define H_DIM 2048
#define H3 6144
#define VOCAB 256
#define NCOMP 256          // compute workgroups, one per CU
#define TPW 768            // 24 rows * 32 lanes/row = 12 waves

typedef unsigned long long u64;

// ---------------- Phase A: table[v][j] = b_ih[j] + sum_e emb[v,e]*w_ih[j,e]
__global__ __launch_bounds__(256) void ih_table_kernel(
    const float* __restrict__ emb, const float* __restrict__ w_ih,
    const float* __restrict__ b_ih, float* __restrict__ table)
{
    __shared__ float As[32][65];
    __shared__ float Bs[32][65];
    const int v0 = blockIdx.y * 64;
    const int j0 = blockIdx.x * 64;
    const int t  = threadIdx.x;
    const int tx = t % 16, ty = t / 16;
    const int lr0 = t / 8;
    const int lc  = (t % 8) * 4;
    float acc[4][4] = {};

    for (int k0 = 0; k0 < E_DIM; k0 += 32) {
        __syncthreads();
#pragma unroll
        for (int p = 0; p < 2; ++p) {
            int r = lr0 + p * 32;
            float4 a = *(const float4*)(emb  + (size_t)(v0 + r) * E_DIM + k0 + lc);
            As[lc+0][r] = a.x; As[lc+1][r] = a.y; As[lc+2][r] = a.z; As[lc+3][r] = a.w;
            float4 b = *(const float4*)(w_ih + (size_t)(j0 + r) * E_DIM + k0 + lc);
            Bs[lc+0][r] = b.x; Bs[lc+1][r] = b.y; Bs[lc+2][r] = b.z; Bs[lc+3][r] = b.w;
        }
        __syncthreads();
#pragma unroll 8
        for (int kk = 0; kk < 32; ++kk) {
            float a4[4], b4[4];
#pragma unroll
            for (int i = 0; i < 4; ++i) a4[i] = As[kk][ty * 4 + i];
#pragma unroll
            for (int i = 0; i < 4; ++i) b4[i] = Bs[kk][tx * 4 + i];
#pragma unroll
            for (int i = 0; i < 4; ++i)
#pragma unroll
                for (int j = 0; j < 4; ++j) acc[i][j] += a4[i] * b4[j];
        }
    }
    const int j = j0 + tx * 4;
    float4 bias = *(const float4*)(b_ih + j);
#pragma unroll
    for (int i = 0; i < 4; ++i) {
        int v = v0 + ty * 4 + i;
        float4 o;
        o.x = acc[i][0] + bias.x; o.y = acc[i][1] + bias.y;
        o.z = acc[i][2] + bias.z; o.w = acc[i][3] + bias.w;
        *(float4*)(table + (size_t)v * H3 + j) = o;
    }
}

// ---------------- Phase B: persistent GRU, W_hh resident in VGPRs.
// WG cw owns hidden units [cw*8, cw*8+8) -> 24 rows (r,z,n).
// Thread: row lr = tid>>5 (0..23), lane l = tid&31 owns col-chunks i*32+l.
// Barrier: each WG release-publishes flags[cw] = step; every WG polls all
// 256 flags directly (thread t polls flag t) -- no coordinator hop.
__global__ __launch_bounds__(TPW, 3) void gru_persistent(
    const int* __restrict__ x, const int* __restrict__ lenp,
    const float* __restrict__ w_hh, const float* __restrict__ b_hh,
    const float* __restrict__ table,
    float* hbuf0, float* hbuf1, int* flags)
{
    __shared__ float hsh[H_DIM];
    __shared__ float dots[24];
    const int cw    = blockIdx.x;
    const int tid   = threadIdx.x;
    const int base  = cw * 8;
    const int lr    = tid >> 5;      // 0..23
    const int l     = tid & 31;      // 32 lanes split the 2048 cols
    const int gate  = lr >> 3;       // 0=r 1=z 2=n
    const int uu    = lr & 7;
    const int S     = lenp[0] + 1;   // 1025

    // ---- one-time: W_hh row slice into registers (16 float4 = 64 VGPRs)
    const float4* wrow4 =
        (const float4*)(w_hh + (size_t)(gate * H_DIM + base + uu) * H_DIM);
    float4 w[16];
#pragma unroll
    for (int i = 0; i < 16; ++i) w[i] = wrow4[i * 32 + l];

    float bhr = 0.f, bhz = 0.f, bhn = 0.f;
    if (tid < 8) {
        bhr = b_hh[base + tid];
        bhz = b_hh[H_DIM + base + tid];
        bhn = b_hh[2 * H_DIM + base + tid];
    }

    float* bufs[2] = {hbuf0, hbuf1};

    for (int s = 0; s < S; ++s) {
        // wait until every WG has published h_s (h_0 via stream-ordered memset)
        if (s > 0 && tid < NCOMP) {
            while (__hip_atomic_load(flags + tid * 32, __ATOMIC_RELAXED,
                                     __HIP_MEMORY_SCOPE_AGENT) < s)
                __builtin_amdgcn_s_sleep(1);
        }
        __syncthreads();

        float* cur = bufs[s & 1];
        float* nxt = bufs[(s + 1) & 1];

        // stage h_s into LDS (agent-scope 8B loads: bypass stale per-XCD L2)
        {
            const u64* src = (const u64*)cur;
            u64* dsh = (u64*)hsh;
            for (int i = tid; i < H_DIM / 2; i += TPW)
                dsh[i] = __hip_atomic_load(src + i, __ATOMIC_RELAXED,
                                           __HIP_MEMORY_SCOPE_AGENT);
        }
        __syncthreads();

        // dot: row lr, lanes 0..31 each cover 16 float4 chunks (stride 32)
        const float4* h4 = (const float4*)hsh;
        float4 a = make_float4(0.f, 0.f, 0.f, 0.f);
#pragma unroll
        for (int i = 0; i < 16; ++i) {
            float4 hv = h4[i * 32 + l];
            a.x += w[i].x * hv.x; a.y += w[i].y * hv.y;
            a.z += w[i].z * hv.z; a.w += w[i].w * hv.w;
        }
        float p = (a.x + a.y) + (a.z + a.w);
        p += __shfl_xor(p, 1);
        p += __shfl_xor(p, 2);
        p += __shfl_xor(p, 4);
        p += __shfl_xor(p, 8);
        p += __shfl_xor(p, 16);
        if (l == 0) dots[lr] = p;
        __syncthreads();

        if (tid < 8) {
            const int u = base + tid;
            const float* trow = table + (size_t)x[s] * H3;
            float ihr = trow[u];
            float ihz = trow[H_DIM + u];
            float ihn = trow[2 * H_DIM + u];
            float hr = dots[tid]      + bhr;
            float hz = dots[8 + tid]  + bhz;
            float hn = dots[16 + tid] + bhn;
            float r_ = 1.f / (1.f + expf(-(ihr + hr)));
            float z_ = 1.f / (1.f + expf(-(ihz + hz)));
            float n_ = tanhf(ihn + r_ * hn);
            float hnew = (1.f - z_) * n_ + z_ * hsh[u];
            __hip_atomic_store(nxt + u, hnew, __ATOMIC_RELAXED,
                               __HIP_MEMORY_SCOPE_AGENT);
        }
        __syncthreads();  // drains vmcnt: the 8 h-stores are agent-visible
        if (tid == 0) {
            __threadfence();
            __hip_atomic_store(flags + cw * 32, s + 1, __ATOMIC_RELAXED,
                               __HIP_MEMORY_SCOPE_AGENT);
        }
    }
}

// ---------------- Epilogue: out = [dec_emb[2] (1024) | h_final (2048)]
__global__ void epilogue_kernel(const int* __restrict__ lenp,
                                const float* __restrict__ dec_emb,
                                const float* __restrict__ hbuf0,
                                const float* __restrict__ hbuf1,
                                float* __restrict__ out)
{
    int i = blockIdx.x * blockDim.x + threadIdx.x;
    int S = lenp[0] + 1;
    const float* hb = (S & 1) ? hbuf1 : hbuf0;
    if (i < E_DIM) out[i] = dec_emb[2 * E_DIM + i];
    else if (i < E_DIM + H_DIM) out[i] = hb[i - E_DIM];
}

extern "C" void kernel_launch(void* const* d_in, const int* in_sizes, int n_in,
                              void* d_out, int out_size, void* d_ws, size_t ws_size,
                              hipStream_t stream) {
    const int*   x       = (const int*)d_in[0];
    const int*   lenp    = (const int*)d_in[1];
    const float* emb     = (const float*)d_in[2];
    const float* w_ih    = (const float*)d_in[3];
    const float* w_hh    = (const float*)d_in[4];
    const float* b_ih    = (const float*)d_in[5];
    const float* b_hh    = (const float*)d_in[6];
    const float* dec_emb = (const float*)d_in[7];
    float* out = (float*)d_out;

    char* ws = (char*)d_ws;
    float* table = (float*)ws;                              // 6,291,456 B
    float* hbuf0 = (float*)(ws + (size_t)VOCAB * H3 * 4);
    float* hbuf1 = hbuf0 + H_DIM;
    int*   flags = (int*)(hbuf1 + H_DIM);                   // 256 * 128 B

    // zero h0/h1 + flags (ws is poisoned 0xAA before every call)
    hipMemsetAsync(hbuf0, 0,
                   (size_t)(2 * H_DIM) * 4 + (size_t)NCOMP * 128, stream);

    dim3 gA(H3 / 64, VOCAB / 64);  // (96, 4)
    ih_table_kernel<<<gA, 256, 0, stream>>>(emb, w_ih, b_ih, table);

    gru_persistent<<<dim3(NCOMP), dim3(TPW), 0, stream>>>(
        x, lenp, w_hh, b_hh, table, hbuf0, hbuf1, flags);

    epilogue_kernel<<<12, 256, 0, stream>>>(lenp, dec_emb, hbuf0, hbuf1, out);
}

// Round 5
// 3229.593 us; speedup vs baseline: 7.2322x; 2.1084x over previous
//
#include <hip/hip_runtime.h>
#include <hip/hip_bf16.h>
#include <math.h>

#define E_DIM 1024
#define H_DIM 2048
#define H3 6144
#define VOCAB 256
#define NCOMP 256          // one WG per CU
#define TPW 512            // 8 units * 64 lanes; gates fused per thread

typedef unsigned long long u64;

// ---------------- Phase A: table[v][j] = b_ih[j] + sum_e emb[v,e]*w_ih[j,e]
__global__ __launch_bounds__(256) void ih_table_kernel(
    const float* __restrict__ emb, const float* __restrict__ w_ih,
    const float* __restrict__ b_ih, float* __restrict__ table)
{
    __shared__ float As[32][65];
    __shared__ float Bs[32][65];
    const int v0 = blockIdx.y * 64;
    const int j0 = blockIdx.x * 64;
    const int t  = threadIdx.x;
    const int tx = t % 16, ty = t / 16;
    const int lr0 = t / 8;
    const int lc  = (t % 8) * 4;
    float acc[4][4] = {};

    for (int k0 = 0; k0 < E_DIM; k0 += 32) {
        __syncthreads();
#pragma unroll
        for (int p = 0; p < 2; ++p) {
            int r = lr0 + p * 32;
            float4 a = *(const float4*)(emb  + (size_t)(v0 + r) * E_DIM + k0 + lc);
            As[lc+0][r] = a.x; As[lc+1][r] = a.y; As[lc+2][r] = a.z; As[lc+3][r] = a.w;
            float4 b = *(const float4*)(w_ih + (size_t)(j0 + r) * E_DIM + k0 + lc);
            Bs[lc+0][r] = b.x; Bs[lc+1][r] = b.y; Bs[lc+2][r] = b.z; Bs[lc+3][r] = b.w;
        }
        __syncthreads();
#pragma unroll 8
        for (int kk = 0; kk < 32; ++kk) {
            float a4[4], b4[4];
#pragma unroll
            for (int i = 0; i < 4; ++i) a4[i] = As[kk][ty * 4 + i];
#pragma unroll
            for (int i = 0; i < 4; ++i) b4[i] = Bs[kk][tx * 4 + i];
#pragma unroll
            for (int i = 0; i < 4; ++i)
#pragma unroll
                for (int j = 0; j < 4; ++j) acc[i][j] += a4[i] * b4[j];
        }
    }
    const int j = j0 + tx * 4;
    float4 bias = *(const float4*)(b_ih + j);
#pragma unroll
    for (int i = 0; i < 4; ++i) {
        int v = v0 + ty * 4 + i;
        float4 o;
        o.x = acc[i][0] + bias.x; o.y = acc[i][1] + bias.y;
        o.z = acc[i][2] + bias.z; o.w = acc[i][3] + bias.w;
        *(float4*)(table + (size_t)v * H3 + j) = o;
    }
}

// ---------------- Phase B: persistent GRU.
// h exchanged as u64 {tag:32 | f32 bits:32}: tag==s marks h_s valid. No
// separate flags/fences; double-buffer safety comes from the dependency
// chain (h_{s+2} writes require all h_{s+1} reads require h_s consumed).
// WG cw owns units [cw*8, cw*8+8). Thread = (uu = tid>>6, l = tid&63);
// owns cols {i*64+l}*4 for ALL 3 gates of unit uu -> 24 float4 weights,
// pinned in VGPRs via per-scalar empty-asm (blocks load re-sinking; the
// float4-tied form doesn't compile on gfx950).
__global__ __launch_bounds__(TPW, 2) void gru_persistent(
    const int* __restrict__ x, const int* __restrict__ lenp,
    const float* __restrict__ w_hh, const float* __restrict__ b_hh,
    const float* __restrict__ table,
    u64* hbuf0, u64* hbuf1)
{
    __shared__ float hsh[H_DIM];
    __shared__ float dots[24];
    const int cw   = blockIdx.x;
    const int tid  = threadIdx.x;
    const int base = cw * 8;
    const int uu   = tid >> 6;     // 0..7 unit
    const int l    = tid & 63;     // 0..63 col lane
    const int S    = lenp[0] + 1;  // 1025

    // one-time weight preload: 3 gates x 8 float4 = 96 VGPRs
    float4 wv[3][8];
#pragma unroll
    for (int g = 0; g < 3; ++g) {
        const float4* wr =
            (const float4*)(w_hh + (size_t)(g * H_DIM + base + uu) * H_DIM);
#pragma unroll
        for (int i = 0; i < 8; ++i) wv[g][i] = wr[i * 64 + l];
    }
    // pin: opaque per-scalar so the compiler cannot re-materialize the loads
#pragma unroll
    for (int g = 0; g < 3; ++g)
#pragma unroll
        for (int i = 0; i < 8; ++i)
            asm volatile("" : "+v"(wv[g][i].x), "+v"(wv[g][i].y),
                              "+v"(wv[g][i].z), "+v"(wv[g][i].w));

    float bhr = 0.f, bhz = 0.f, bhn = 0.f;
    if (tid < 8) {
        bhr = b_hh[base + tid];
        bhz = b_hh[H_DIM + base + tid];
        bhn = b_hh[2 * H_DIM + base + tid];
    }

    u64* bufs[2] = {hbuf0, hbuf1};

    for (int s = 0; s < S; ++s) {
        const u64* src = bufs[s & 1];
        u64*       dst = bufs[(s + 1) & 1];

        // prefetch input-side gate values (read-only, L1/L2-hot)
        float ihr = 0.f, ihz = 0.f, ihn = 0.f;
        if (tid < 8) {
            const float* trow = table + (size_t)x[s] * H3;
            ihr = trow[base + tid];
            ihz = trow[H_DIM + base + tid];
            ihn = trow[2 * H_DIM + base + tid];
        }

        // poll + stage h_s: 4 elements per thread, concurrent spins
        {
            const u64 want = (u64)s;
            u64 got[4];
            bool ok[4] = {false, false, false, false};
            for (;;) {
                bool all = true;
#pragma unroll
                for (int j = 0; j < 4; ++j) {
                    if (!ok[j]) {
                        u64 v = __hip_atomic_load(src + tid + j * TPW,
                                                  __ATOMIC_RELAXED,
                                                  __HIP_MEMORY_SCOPE_AGENT);
                        if ((v >> 32) == want) { got[j] = v; ok[j] = true; }
                        else all = false;
                    }
                }
                if (all) break;
                __builtin_amdgcn_s_sleep(1);
            }
#pragma unroll
            for (int j = 0; j < 4; ++j)
                hsh[tid + j * TPW] = __uint_as_float((unsigned)got[j]);
        }
        __syncthreads();

        // fused-gate dot: read each h chunk once, FMA against 3 weight rows
        const float4* h4 = (const float4*)hsh;
        float4 ar = make_float4(0.f, 0.f, 0.f, 0.f);
        float4 az = make_float4(0.f, 0.f, 0.f, 0.f);
        float4 an = make_float4(0.f, 0.f, 0.f, 0.f);
#pragma unroll
        for (int i = 0; i < 8; ++i) {
            float4 hv = h4[i * 64 + l];
            ar.x += wv[0][i].x * hv.x; ar.y += wv[0][i].y * hv.y;
            ar.z += wv[0][i].z * hv.z; ar.w += wv[0][i].w * hv.w;
            az.x += wv[1][i].x * hv.x; az.y += wv[1][i].y * hv.y;
            az.z += wv[1][i].z * hv.z; az.w += wv[1][i].w * hv.w;
            an.x += wv[2][i].x * hv.x; an.y += wv[2][i].y * hv.y;
            an.z += wv[2][i].z * hv.z; an.w += wv[2][i].w * hv.w;
        }
        float pr = (ar.x + ar.y) + (ar.z + ar.w);
        float pz = (az.x + az.y) + (az.z + az.w);
        float pn = (an.x + an.y) + (an.z + an.w);
#pragma unroll
        for (int d = 1; d < 64; d <<= 1) {
            pr += __shfl_xor(pr, d);
            pz += __shfl_xor(pz, d);
            pn += __shfl_xor(pn, d);
        }
        if (l == 0) {
            dots[uu]      = pr;
            dots[8 + uu]  = pz;
            dots[16 + uu] = pn;
        }
        __syncthreads();

        if (tid < 8) {
            float hr = dots[tid]      + bhr;
            float hz = dots[8 + tid]  + bhz;
            float hn = dots[16 + tid] + bhn;
            float r_ = 1.f / (1.f + expf(-(ihr + hr)));
            float z_ = 1.f / (1.f + expf(-(ihz + hz)));
            float n_ = tanhf(ihn + r_ * hn);
            float hnew = (1.f - z_) * n_ + z_ * hsh[base + tid];
            u64 pack = ((u64)(unsigned)(s + 1) << 32) |
                       (u64)__float_as_uint(hnew);
            __hip_atomic_store(dst + base + tid, pack, __ATOMIC_RELAXED,
                               __HIP_MEMORY_SCOPE_AGENT);
        }
        __syncthreads();   // protect hsh/dots from next-iteration overwrite
    }
}

// ---------------- Epilogue: out = [dec_emb[2] (1024) | h_final (2048)]
__global__ void epilogue_kernel(const int* __restrict__ lenp,
                                const float* __restrict__ dec_emb,
                                const u64* __restrict__ hbuf0,
                                const u64* __restrict__ hbuf1,
                                float* __restrict__ out)
{
    int i = blockIdx.x * blockDim.x + threadIdx.x;
    int S = lenp[0] + 1;
    const u64* hb = (S & 1) ? hbuf1 : hbuf0;
    if (i < E_DIM) out[i] = dec_emb[2 * E_DIM + i];
    else if (i < E_DIM + H_DIM)
        out[i] = __uint_as_float((unsigned)hb[i - E_DIM]);
}

extern "C" void kernel_launch(void* const* d_in, const int* in_sizes, int n_in,
                              void* d_out, int out_size, void* d_ws, size_t ws_size,
                              hipStream_t stream) {
    const int*   x       = (const int*)d_in[0];
    const int*   lenp    = (const int*)d_in[1];
    const float* emb     = (const float*)d_in[2];
    const float* w_ih    = (const float*)d_in[3];
    const float* w_hh    = (const float*)d_in[4];
    const float* b_ih    = (const float*)d_in[5];
    const float* b_hh    = (const float*)d_in[6];
    const float* dec_emb = (const float*)d_in[7];
    float* out = (float*)d_out;

    char* ws = (char*)d_ws;
    float* table = (float*)ws;                              // 6,291,456 B
    u64*   hbuf0 = (u64*)(ws + (size_t)VOCAB * H3 * 4);     // 2048 u64
    u64*   hbuf1 = hbuf0 + H_DIM;                           // 2048 u64

    // zero both tagged h buffers: h_0 = {tag 0, 0.0f} (ws poisoned 0xAA)
    hipMemsetAsync(hbuf0, 0, (size_t)2 * H_DIM * sizeof(u64), stream);

    dim3 gA(H3 / 64, VOCAB / 64);  // (96, 4)
    ih_table_kernel<<<gA, 256, 0, stream>>>(emb, w_ih, b_ih, table);

    gru_persistent<<<dim3(NCOMP), dim3(TPW), 0, stream>>>(
        x, lenp, w_hh, b_hh, table, hbuf0, hbuf1);

    epilogue_kernel<<<12, 256, 0, stream>>>(lenp, dec_emb, hbuf0, hbuf1, out);
}